// Round 2
// baseline (291.154 us; speedup 1.0000x reference)
//
#include <hip/hip_runtime.h>
#include <cstdint>

#define DIMC 2048
#define NSEQ 2048
#define BATCH 2
#define NH 16
#define HD 128
#define MROWS 4096            // BATCH*NSEQ
#define NQKV 6144             // 3*DIMC
#define QSCALE 0.08838834764831845f

typedef float f32x4 __attribute__((ext_vector_type(4)));
typedef __bf16 bf16x8 __attribute__((ext_vector_type(8)));
typedef __bf16 bf16x4 __attribute__((ext_vector_type(4)));

__device__ __forceinline__ f32x4 mfma16(bf16x8 a, bf16x8 b, f32x4 c) {
  return __builtin_amdgcn_mfma_f32_16x16x32_bf16(a, b, c, 0, 0, 0);
}

typedef __attribute__((address_space(1))) void gvoid;
typedef __attribute__((address_space(3))) void ldsvoid;

// global -> LDS direct copy, 16B per lane; lds base must be wave-uniform.
__device__ __forceinline__ void async16(void* lds, const void* g) {
  __builtin_amdgcn_global_load_lds((gvoid*)(uintptr_t)g, (ldsvoid*)(uintptr_t)lds, 16, 0, 0);
}

// ---------------------------------------------------------------------------
// fp32 -> bf16 cast, vectorized
// ---------------------------------------------------------------------------
__global__ __launch_bounds__(256) void cast_bf16(const float* __restrict__ src,
                                                 __bf16* __restrict__ dst, int n) {
  int i = (blockIdx.x * 256 + threadIdx.x) * 4;
  const int stride = gridDim.x * 1024;
  for (; i < n; i += stride) {
    const float4 v = *(const float4*)(src + i);
    bf16x4 o = {(__bf16)v.x, (__bf16)v.y, (__bf16)v.z, (__bf16)v.w};
    *(bf16x4*)(dst + i) = o;
  }
}

// ---------------------------------------------------------------------------
// GEMM  C[M][N] = A[M][K] * B[N][K]^T (+bias), K = 2048, 128x128 tile (m97)
// EPI 0: QKV epilogue (bias, Q*scale, scatter to Q[B,H,N,D], K[B,H,N,D],
//        Vt[B,H,D,N] as bf16)
// EPI 1: out epilogue (bias, fp32 to d_out)
// ---------------------------------------------------------------------------
template <int EPI>
__global__ __launch_bounds__(256) void gemm_bt(
    const __bf16* __restrict__ A, const __bf16* __restrict__ Bm,
    __bf16* __restrict__ Qb, __bf16* __restrict__ Kb, __bf16* __restrict__ Vtb,
    const float* __restrict__ bias0, const float* __restrict__ bias1,
    const float* __restrict__ bias2, float* __restrict__ outp) {
  __shared__ __bf16 Al[128 * 32];
  __shared__ __bf16 Bl[128 * 32];
  const int tid = threadIdx.x;
  const int w = tid >> 6, l = tid & 63;
  const int a = l & 15, g = l >> 4;
  const int mbase = blockIdx.y * 128, nbase = blockIdx.x * 128;
  const int wr = w >> 1, wc = w & 1;

  f32x4 acc[4][4] = {};

  const char* Ag = (const char*)A +
      ((size_t)(mbase + w * 32 + (l >> 2)) * DIMC + (size_t)(l & 3) * 8) * 2;
  const char* Bg = (const char*)Bm +
      ((size_t)(nbase + w * 32 + (l >> 2)) * DIMC + (size_t)(l & 3) * 8) * 2;
  char* Alw = (char*)Al + w * 2048;
  char* Blw = (char*)Bl + w * 2048;

  for (int kt = 0; kt < DIMC / 32; ++kt) {
    const size_t ko = (size_t)kt * 64;
    async16(Alw, Ag + ko);
    async16(Alw + 1024, Ag + (size_t)16 * (DIMC * 2) + ko);
    async16(Blw, Bg + ko);
    async16(Blw + 1024, Bg + (size_t)16 * (DIMC * 2) + ko);
    __syncthreads();
    bf16x8 af[4], bf_[4];
#pragma unroll
    for (int m = 0; m < 4; ++m)
      af[m] = *(const bf16x8*)((const char*)Al + (wr * 64 + m * 16 + a) * 64 + g * 16);
#pragma unroll
    for (int n = 0; n < 4; ++n)
      bf_[n] = *(const bf16x8*)((const char*)Bl + (wc * 64 + n * 16 + a) * 64 + g * 16);
#pragma unroll
    for (int m = 0; m < 4; ++m)
#pragma unroll
      for (int n = 0; n < 4; ++n) acc[m][n] = mfma16(af[m], bf_[n], acc[m][n]);
    __syncthreads();
  }

  if constexpr (EPI == 0) {
    const int seg = nbase >> 11;               // 0=q 1=k 2=v
    const int cin = (nbase & 2047) + wc * 64;  // channel base in segment
    const float* bias = (seg == 0) ? bias0 : ((seg == 1) ? bias1 : bias2);
    const float scl = (seg == 0) ? QSCALE : 1.0f;
#pragma unroll
    for (int n = 0; n < 4; ++n) {
      const int c = cin + n * 16 + a;
      const float bb = bias[c];
      const int h = c >> 7, d = c & 127;
#pragma unroll
      for (int m = 0; m < 4; ++m) {
        const int mr = mbase + wr * 64 + m * 16 + g * 4;
        const int b_ = mr >> 11, sq = mr & 2047;
        f32x4 v = acc[m][n];
        if (seg == 2) {
          __bf16* dst = Vtb + ((size_t)(b_ * NH + h) * HD + d) * NSEQ + sq;
          bf16x4 pk = {(__bf16)(v[0] + bb), (__bf16)(v[1] + bb),
                       (__bf16)(v[2] + bb), (__bf16)(v[3] + bb)};
          *(bf16x4*)dst = pk;
        } else {
          __bf16* dst = ((seg == 0) ? Qb : Kb) +
                        ((size_t)(b_ * NH + h) * NSEQ + sq) * HD + d;
#pragma unroll
          for (int j = 0; j < 4; ++j) dst[(size_t)j * HD] = (__bf16)((v[j] + bb) * scl);
        }
      }
    }
  } else {
#pragma unroll
    for (int n = 0; n < 4; ++n) {
      const int c = nbase + wc * 64 + n * 16 + a;
      const float bb = bias0[c];
#pragma unroll
      for (int m = 0; m < 4; ++m) {
        const int mr = mbase + wr * 64 + m * 16 + g * 4;
        float* dst = outp + (size_t)mr * DIMC + c;
        f32x4 v = acc[m][n];
#pragma unroll
        for (int j = 0; j < 4; ++j) dst[(size_t)j * DIMC] = v[j] + bb;
      }
    }
  }
}

// ---------------------------------------------------------------------------
// Sliding-window flash attention.
// Q[B,H,N,D] (pre-scaled), K[B,H,N,D], Vt[B,H,D,N] bf16 -> O[B,N,H*D] bf16.
// Block: 64 q-rows (4 waves x 16), KV tiles of 64. Window: kv in [q-1024, q].
// ---------------------------------------------------------------------------
__global__ __launch_bounds__(256) void attn_swa(const __bf16* __restrict__ Qb,
                                                const __bf16* __restrict__ Kb,
                                                const __bf16* __restrict__ Vtb,
                                                __bf16* __restrict__ Ob) {
  __shared__ __bf16 Klds[64 * 128];   // [kv][d], 16B-chunk XOR swizzled
  __shared__ __bf16 Vlds[128 * 64];   // [d][kv], 16B-chunk XOR swizzled
  __shared__ __bf16 Plds[4 * 16 * 64];  // per-wave [16 q][64 kv], swizzled
  const int tid = threadIdx.x;
  const int w = tid >> 6, l = tid & 63;
  const int a = l & 15, g = l >> 4;
  const int bh = blockIdx.y;
  const int qbase = blockIdx.x * 64;
  const __bf16* Qg = Qb + (size_t)bh * NSEQ * HD + (size_t)qbase * HD;
  const __bf16* Kg = Kb + (size_t)bh * NSEQ * HD;
  const __bf16* Vg = Vtb + (size_t)bh * HD * NSEQ;

  bf16x8 qf[4];
#pragma unroll
  for (int s = 0; s < 4; ++s)
    qf[s] = *(const bf16x8*)(Qg + (size_t)(w * 16 + a) * HD + s * 32 + g * 8);

  float mrow[4] = {-1e38f, -1e38f, -1e38f, -1e38f};
  float lrow[4] = {0.f, 0.f, 0.f, 0.f};
  f32x4 o[8] = {};

  const int ktlo = (qbase >= 1024) ? ((qbase - 1024) >> 6) : 0;
  const int kthi = qbase >> 6;
  const int qmax = qbase + 63;

  for (int kt = ktlo; kt <= kthi; ++kt) {
    const int kb = kt * 64;
    // stage K tile [64][128]
#pragma unroll
    for (int j = 0; j < 4; ++j) {
      const int off = j * 4096 + w * 1024 + l * 16;
      const int row = off >> 8;
      const int cg = ((off >> 4) & 15) ^ (row & 7);
      async16((char*)Klds + j * 4096 + w * 1024,
              (const char*)Kg + (size_t)(kb + row) * 256 + cg * 16);
    }
    // stage Vt tile [128][64]
#pragma unroll
    for (int j = 0; j < 4; ++j) {
      const int off = j * 4096 + w * 1024 + l * 16;
      const int row = off >> 7;
      const int cg = ((off >> 4) & 7) ^ (row & 7);
      async16((char*)Vlds + j * 4096 + w * 1024,
              (const char*)Vg + (size_t)row * (NSEQ * 2) + (size_t)kb * 2 + cg * 16);
    }
    __syncthreads();

    const bool full = (kb >= qmax - 1024) && (kb + 63 <= qbase);
    f32x4 s4[4];
#pragma unroll
    for (int t = 0; t < 4; ++t) {
      f32x4 sc = {};
#pragma unroll
      for (int ds = 0; ds < 4; ++ds) {
        const int row = t * 16 + a;
        const int ch = (ds * 4 + g) ^ (row & 7);
        bf16x8 kf = *(const bf16x8*)((const char*)Klds + row * 256 + ch * 16);
        sc = mfma16(qf[ds], kf, sc);
      }
      s4[t] = sc;
    }
    if (!full) {
#pragma unroll
      for (int t = 0; t < 4; ++t)
#pragma unroll
        for (int i = 0; i < 4; ++i) {
          const int q = qbase + w * 16 + g * 4 + i;
          const int kv = kb + t * 16 + a;
          if (kv > q || kv + 1024 < q) s4[t][i] = -1e30f;
        }
    }
    float pm[4], corr[4], rs[4];
#pragma unroll
    for (int i = 0; i < 4; ++i)
      pm[i] = fmaxf(fmaxf(s4[0][i], s4[1][i]), fmaxf(s4[2][i], s4[3][i]));
#pragma unroll
    for (int i = 0; i < 4; ++i) {
      pm[i] = fmaxf(pm[i], __shfl_xor(pm[i], 1));
      pm[i] = fmaxf(pm[i], __shfl_xor(pm[i], 2));
      pm[i] = fmaxf(pm[i], __shfl_xor(pm[i], 4));
      pm[i] = fmaxf(pm[i], __shfl_xor(pm[i], 8));
      const float nm = fmaxf(mrow[i], pm[i]);
      corr[i] = __expf(mrow[i] - nm);
      mrow[i] = nm;
      rs[i] = 0.f;
    }
#pragma unroll
    for (int t = 0; t < 4; ++t)
#pragma unroll
      for (int i = 0; i < 4; ++i) {
        const float p = __expf(s4[t][i] - mrow[i]);
        s4[t][i] = p;
        rs[i] += p;
      }
#pragma unroll
    for (int i = 0; i < 4; ++i) {
      rs[i] += __shfl_xor(rs[i], 1);
      rs[i] += __shfl_xor(rs[i], 2);
      rs[i] += __shfl_xor(rs[i], 4);
      rs[i] += __shfl_xor(rs[i], 8);
      lrow[i] = lrow[i] * corr[i] + rs[i];
    }
#pragma unroll
    for (int n = 0; n < 8; ++n)
#pragma unroll
      for (int i = 0; i < 4; ++i) o[n][i] *= corr[i];
    // write P (bf16) to per-wave LDS, chunk-swizzled; then PV
    char* Pw = (char*)Plds + w * 2048;
#pragma unroll
    for (int t = 0; t < 4; ++t)
#pragma unroll
      for (int i = 0; i < 4; ++i) {
        const int q = g * 4 + i;
        const int byte = (q * 128 + (t * 16 + a) * 2) ^ ((q & 7) << 4);
        *(__bf16*)(Pw + byte) = (__bf16)s4[t][i];
      }
#pragma unroll
    for (int ks = 0; ks < 2; ++ks) {
      const int ch = (ks * 4 + g) ^ (a & 7);
      bf16x8 pa = *(const bf16x8*)(Pw + a * 128 + ch * 16);
#pragma unroll
      for (int n = 0; n < 8; ++n) {
        const int row = n * 16 + a;
        const int vch = (ks * 4 + g) ^ (row & 7);
        bf16x8 vf = *(const bf16x8*)((const char*)Vlds + row * 128 + vch * 16);
        o[n] = mfma16(pa, vf, o[n]);
      }
    }
    __syncthreads();
  }

  const int b_ = bh >> 4, h = bh & 15;
  __bf16* Og = Ob + (size_t)(b_ * NSEQ + qbase + w * 16 + g * 4) * DIMC + h * HD;
#pragma unroll
  for (int i = 0; i < 4; ++i) {
    const float inv = 1.f / lrow[i];
#pragma unroll
    for (int n = 0; n < 8; ++n)
      Og[(size_t)i * DIMC + n * 16 + a] = (__bf16)(o[n][i] * inv);
  }
}

// ---------------------------------------------------------------------------
extern "C" void kernel_launch(void* const* d_in, const int* in_sizes, int n_in,
                              void* d_out, int out_size, void* d_ws, size_t ws_size,
                              hipStream_t stream) {
  const float* x = (const float*)d_in[0];
  const float* Wq = (const float*)d_in[1];
  const float* bq = (const float*)d_in[2];
  const float* Wk = (const float*)d_in[3];
  const float* bk = (const float*)d_in[4];
  const float* Wv = (const float*)d_in[5];
  const float* bv = (const float*)d_in[6];
  const float* Wo = (const float*)d_in[7];
  const float* bo = (const float*)d_in[8];
  float* out = (float*)d_out;

  char* ws = (char*)d_ws;
  __bf16* xb    = (__bf16*)(ws + 0);          // 16.78 MB (reused as Ob)
  __bf16* Wqkvb = (__bf16*)(ws + 16777216);   // 25.17 MB
  __bf16* Wob   = (__bf16*)(ws + 41943040);   // 8.39 MB
  __bf16* Qb    = (__bf16*)(ws + 50331648);   // 16.78 MB
  __bf16* Kb    = (__bf16*)(ws + 67108864);   // 16.78 MB
  __bf16* Vtb   = (__bf16*)(ws + 83886080);   // 16.78 MB -> total 100.66 MB
  __bf16* Ob    = xb;

  cast_bf16<<<dim3(2048), 256, 0, stream>>>(x, xb, MROWS * DIMC);
  cast_bf16<<<dim3(1024), 256, 0, stream>>>(Wq, Wqkvb, DIMC * DIMC);
  cast_bf16<<<dim3(1024), 256, 0, stream>>>(Wk, Wqkvb + (size_t)DIMC * DIMC, DIMC * DIMC);
  cast_bf16<<<dim3(1024), 256, 0, stream>>>(Wv, Wqkvb + (size_t)2 * DIMC * DIMC, DIMC * DIMC);
  cast_bf16<<<dim3(1024), 256, 0, stream>>>(Wo, Wob, DIMC * DIMC);

  gemm_bt<0><<<dim3(NQKV / 128, MROWS / 128), 256, 0, stream>>>(
      xb, Wqkvb, Qb, Kb, Vtb, bq, bk, bv, nullptr);

  attn_swa<<<dim3(NSEQ / 64, BATCH * NH), 256, 0, stream>>>(Qb, Kb, Vtb, Ob);

  gemm_bt<1><<<dim3(DIMC / 128, MROWS / 128), 256, 0, stream>>>(
      Ob, Wob, nullptr, nullptr, nullptr, bo, nullptr, nullptr, out);
}